// Round 2
// baseline (1495.318 us; speedup 1.0000x reference)
//
#include <hip/hip_runtime.h>
#include <hip/hip_bf16.h>
#include <cmath>

typedef __bf16 bf16x8 __attribute__((ext_vector_type(8)));
typedef unsigned short u16x8_t __attribute__((ext_vector_type(8)));
typedef float f32x4 __attribute__((ext_vector_type(4)));
typedef unsigned short u16;

__device__ inline bf16x8 ld16(const void* p) {
  return __builtin_bit_cast(bf16x8, *reinterpret_cast<const u16x8_t*>(p));
}
__device__ inline void async16(const void* g, void* l) {
  __builtin_amdgcn_global_load_lds(
      (const __attribute__((address_space(1))) unsigned int*)g,
      (__attribute__((address_space(3))) unsigned int*)l, 16, 0, 0);
}
__device__ inline u16 f2bf(float v) {
  return __builtin_bit_cast(u16, __float2bfloat16(v));
}
__device__ inline float bf2f(u16 v) {
  unsigned int u = ((unsigned int)v) << 16;
  return __builtin_bit_cast(float, u);
}

// ---------------- cast f32 -> bf16 (vectorized, zero-pad past nsrc) ----------
__global__ void cast4(const float* __restrict__ src, u16* __restrict__ dst,
                      long n, long nsrc) {
  for (long i = (long)blockIdx.x * 256 + threadIdx.x; i * 4 < n;
       i += (long)gridDim.x * 256) {
    float4 v;
    if (i * 4 < nsrc) v = ((const float4*)src)[i];
    else { v.x = v.y = v.z = v.w = 0.f; }
    ushort4 o;
    o.x = f2bf(v.x); o.y = f2bf(v.y); o.z = f2bf(v.z); o.w = f2bf(v.w);
    ((ushort4*)dst)[i] = o;
  }
}

__global__ void fill_dbg(float* __restrict__ out, long n, float v) {
  for (long i = (long)blockIdx.x * 256 + threadIdx.x; i < n;
       i += (long)gridDim.x * 256) out[i] = v;
}

// ---------------- wkv_b -> per-head transposed nope part + v part ------------
// in: f32 [16*256][512]. outT bf16 [16][512][128] = in[h*256+d][c] (d<128)
//                        outV bf16 [16][128][512] = in[h*256+128+d][c]
__global__ void prep_wkvb(const float* __restrict__ in, u16* __restrict__ outT,
                          u16* __restrict__ outV) {
  int h = blockIdx.x >> 7, d = blockIdx.x & 127;
  const float* r0 = in + (long)(h * 256 + d) * 512;
  const float* r1 = in + (long)(h * 256 + 128 + d) * 512;
  for (int c = threadIdx.x; c < 512; c += 256) {
    outT[((long)h * 512 + c) * 128 + d] = f2bf(r0[c]);
    outV[((long)h * 128 + d) * 512 + c] = f2bf(r1[c]);
  }
}

// ---------------- generic C = A * B^T bf16 GEMM (m97 structure) --------------
template <bool OUT_BF16>
__global__ __launch_bounds__(256) void gemm_bt(
    const u16* __restrict__ A, long lda,
    const u16* __restrict__ B, long ldb,
    void* __restrict__ Cv, long ldc, int K) {
  const long m0 = (long)blockIdx.y * 128, n0 = (long)blockIdx.x * 128;
  __shared__ __align__(16) u16 As[128][32];
  __shared__ __align__(16) u16 Bs[128][32];
  const int tid = threadIdx.x, lane = tid & 63, wv = tid >> 6;
  const int wm = (wv >> 1) * 64, wn = (wv & 1) * 64;
  const int lr = lane & 15, lg = lane >> 4;
  f32x4 acc[4][4];
#pragma unroll
  for (int i = 0; i < 4; i++)
#pragma unroll
    for (int j = 0; j < 4; j++) acc[i][j] = f32x4{0.f, 0.f, 0.f, 0.f};
  const int rr = tid >> 2, ko = (tid & 3) * 8;
  for (int k0 = 0; k0 < K; k0 += 32) {
    __syncthreads();
    async16(A + (m0 + rr) * lda + k0 + ko, &As[rr][ko]);
    async16(A + (m0 + rr + 64) * lda + k0 + ko, &As[rr + 64][ko]);
    async16(B + (n0 + rr) * ldb + k0 + ko, &Bs[rr][ko]);
    async16(B + (n0 + rr + 64) * ldb + k0 + ko, &Bs[rr + 64][ko]);
    __syncthreads();
    bf16x8 af[4], bfr[4];
#pragma unroll
    for (int mi = 0; mi < 4; mi++) af[mi] = ld16(&As[wm + mi * 16 + lr][lg * 8]);
#pragma unroll
    for (int ni = 0; ni < 4; ni++) bfr[ni] = ld16(&Bs[wn + ni * 16 + lr][lg * 8]);
#pragma unroll
    for (int mi = 0; mi < 4; mi++)
#pragma unroll
      for (int ni = 0; ni < 4; ni++)
        acc[mi][ni] = __builtin_amdgcn_mfma_f32_16x16x32_bf16(
            af[mi], bfr[ni], acc[mi][ni], 0, 0, 0);
  }
#pragma unroll
  for (int mi = 0; mi < 4; mi++)
#pragma unroll
    for (int ni = 0; ni < 4; ni++)
#pragma unroll
      for (int j = 0; j < 4; j++) {
        long row = m0 + wm + mi * 16 + lg * 4 + j;
        long col = n0 + wn + ni * 16 + lr;
        long idx = row * ldc + col;
        if (OUT_BF16) ((u16*)Cv)[idx] = f2bf(acc[mi][ni][j]);
        else ((float*)Cv)[idx] = acc[mi][ni][j];
      }
}

// ---------------- q fixup: split nope/pe, RoPE pe (bf16 in) ------------------
// q bf16 [4096][3072] (col = h*192+j) -> qn bf16 [4096][16][128], qpe [..][64]
__global__ void fixup_q(const u16* __restrict__ q, const float* __restrict__ freqs,
                        u16* __restrict__ qn, u16* __restrict__ qpe) {
  long row = blockIdx.x;
  int s = (int)(row & 2047);
  const u16* qr = q + row * 3072;
  for (int j = threadIdx.x; j < 2048; j += 256) {
    int h = j >> 7, d = j & 127;
    qn[row * 2048 + j] = qr[h * 192 + d];
  }
  for (int j = threadIdx.x; j < 1024; j += 256) {
    int h = j >> 6, t = j & 63, p = t >> 1;
    float ang = freqs[s * 32 + p];
    float co = cosf(ang), sn = sinf(ang);
    float x0 = bf2f(qr[h * 192 + 128 + 2 * p]);
    float x1 = bf2f(qr[h * 192 + 128 + 2 * p + 1]);
    float y = (t & 1) ? (x0 * sn + x1 * co) : (x0 * co - x1 * sn);
    qpe[row * 1024 + j] = f2bf(y);
  }
}

// ---------------- kv fixup: RMSNorm(kv)*w -> bf16, RoPE(k_pe) -> bf16 --------
__global__ void fixup_kv(const float* __restrict__ kvf, const float* __restrict__ w,
                         const float* __restrict__ freqs, u16* __restrict__ kvn,
                         u16* __restrict__ kpe) {
  long row = blockIdx.x;
  int s = (int)(row & 2047);
  const float* src = kvf + row * 640;
  int t = threadIdx.x;
  float x0 = src[t], x1 = src[t + 256];
  float ss = x0 * x0 + x1 * x1;
  for (int d = 1; d < 64; d <<= 1) ss += __shfl_xor(ss, d);
  __shared__ float wsum[4];
  if ((t & 63) == 0) wsum[t >> 6] = ss;
  __syncthreads();
  float tot = wsum[0] + wsum[1] + wsum[2] + wsum[3];
  float inv = rsqrtf(tot * (1.0f / 512.0f) + 1e-6f);
  kvn[row * 512 + t] = f2bf(x0 * inv * w[t]);
  kvn[row * 512 + t + 256] = f2bf(x1 * inv * w[t + 256]);
  if (t < 64) {
    int p = t >> 1;
    float ang = freqs[s * 32 + p];
    float co = cosf(ang), sn = sinf(ang);
    float a0 = src[512 + 2 * p], a1 = src[512 + 2 * p + 1];
    float y = (t & 1) ? (a0 * sn + a1 * co) : (a0 * co - a1 * sn);
    kpe[row * 64 + t] = f2bf(y);
  }
}

// ---------------- kvn [4096][512] -> kvt [2][512][2048] (per-batch T) --------
__global__ void transpose_kv(const u16* __restrict__ kvn, u16* __restrict__ kvt) {
  __shared__ u16 T[32][33];
  int b = blockIdx.z;
  int s0 = blockIdx.x * 32, c0 = blockIdx.y * 32;
  int r = threadIdx.x >> 5, c = threadIdx.x & 31;
  for (int rr = r; rr < 32; rr += 8)
    T[rr][c] = kvn[((long)b * 2048 + s0 + rr) * 512 + c0 + c];
  __syncthreads();
  for (int rr = r; rr < 32; rr += 8)
    kvt[((long)b * 512 + c0 + rr) * 2048 + s0 + c] = T[c][rr];
}

// ---------------- fused flash MLA attention ----------------------------------
// Per block (one 32-row q-tile, one head h, one batch b):
//  P1: q_abs = qn @ wbT[h]^T (32x512, K=128) -> LDS (swizzled)
//  P2: load Q fragments (q_abs from LDS, q_pe from global)
//  P3: flash loop over 32-row K/V tiles (QK^T -> online softmax -> PV)
//  P4: O(32x512) -> LDS; ov = O @ wbV[h]^T (32x128, K=512) -> global
// Wave (qg in 0..1, cg in 0..3): qg = 16 q-rows, cg = col-slice.
__device__ inline int swz(int row, int col) {  // within [32][512] u16 tile
  return row * 512 + ((((col >> 3) ^ (row & 7)) << 3) | (col & 7));
}

__global__ __launch_bounds__(512, 2) void mla_flash(
    const u16* __restrict__ qn, const u16* __restrict__ qpe,
    const u16* __restrict__ wbT, const u16* __restrict__ wbV,
    const u16* __restrict__ kvn, const u16* __restrict__ kpe,
    const u16* __restrict__ kvt, u16* __restrict__ ov, float scale) {
  __shared__ __align__(16) u16 Ks[32][576];    // 36864 B, chunk-XOR swizzled
  __shared__ __align__(16) u16 Vts[512][32];   // 32768 B, linear
  __shared__ __align__(16) u16 Pl[8][16][40];  // 10240 B
  u16* KQ = &Ks[0][0];  // overlay: Qa / Ot [32][512] swizzled (32768 B)

  const int qb = blockIdx.x * 32;
  const int h = blockIdx.y, b = blockIdx.z;
  const int tid = threadIdx.x, lane = tid & 63, wv = tid >> 6;
  const int qg = wv >> 2, cg = wv & 3;
  const int lr = lane & 15, lg = lane >> 4;
  const long rowA = (long)b * 2048 + qb + qg * 16 + lr;  // A-frag q row
  const int qrowD = qb + qg * 16 + lg * 4;               // D-frag q row (+j)

  // ---- P1: q_abs tile -> LDS ----
  {
    f32x4 qacc[8];
#pragma unroll
    for (int i = 0; i < 8; i++) qacc[i] = f32x4{0.f, 0.f, 0.f, 0.f};
#pragma unroll
    for (int ks = 0; ks < 4; ks++) {
      bf16x8 aq = ld16(qn + rowA * 2048 + h * 128 + ks * 32 + lg * 8);
#pragma unroll
      for (int ni = 0; ni < 8; ni++) {
        bf16x8 bw = ld16(wbT + ((long)h * 512 + cg * 128 + ni * 16 + lr) * 128 +
                         ks * 32 + lg * 8);
        qacc[ni] = __builtin_amdgcn_mfma_f32_16x16x32_bf16(aq, bw, qacc[ni], 0, 0, 0);
      }
    }
#pragma unroll
    for (int ni = 0; ni < 8; ni++)
#pragma unroll
      for (int j = 0; j < 4; j++)
        KQ[swz(qg * 16 + lg * 4 + j, cg * 128 + ni * 16 + lr)] = f2bf(qacc[ni][j]);
  }
  __syncthreads();

  // ---- P2: Q fragments ----
  bf16x8 qf[18];
#pragma unroll
  for (int f = 0; f < 16; f++)
    qf[f] = ld16(&KQ[swz(qg * 16 + lr, f * 32 + lg * 8)]);
  {
    const u16* qp = qpe + rowA * 1024 + h * 64 + lg * 8;
    qf[16] = ld16(qp);
    qf[17] = ld16(qp + 32);
  }

  f32x4 O[8];
#pragma unroll
  for (int i = 0; i < 8; i++) O[i] = f32x4{0.f, 0.f, 0.f, 0.f};
  float mrow[4], lrow[4];
#pragma unroll
  for (int j = 0; j < 4; j++) { mrow[j] = -INFINITY; lrow[j] = 0.f; }

  const int nt = qb / 32 + 1;
  for (int t = 0; t < nt; t++) {
    const int tb = t * 32;
    __syncthreads();
    // stage K-tile [32][576] with per-row 16B-chunk swizzle o ^= (r&7)
    for (int c = tid; c < 2304; c += 512) {
      int r = c / 72, o = c - r * 72;
      int og = o ^ (r & 7);
      long grow = (long)b * 2048 + tb + r;
      const u16* src = (og < 64) ? (kvn + grow * 512 + og * 8)
                                 : (kpe + grow * 64 + (og - 64) * 8);
      async16(src, ((char*)&Ks[0][0]) + (long)c * 16);
    }
    // stage V^T tile [512][32] (linear)
    for (int c = tid; c < 2048; c += 512) {
      int r = c >> 2, o = c & 3;
      const u16* src = kvt + ((long)b * 512 + r) * 2048 + tb + o * 8;
      async16(src, ((char*)&Vts[0][0]) + (long)c * 16);
    }
    __syncthreads();

    // QK^T (redundant across cg waves)
    f32x4 sc[2];
    sc[0] = f32x4{0.f, 0.f, 0.f, 0.f};
    sc[1] = f32x4{0.f, 0.f, 0.f, 0.f};
    {
      const char* base0 = ((const char*)&Ks[0][0]) + lr * 1152;
      const int sx = (lr & 7) * 16;
#pragma unroll
      for (int f = 0; f < 18; f++) {
        int co = ((f * 4 + lg) * 16) ^ sx;
        bf16x8 k0 = ld16(base0 + co);
        bf16x8 k1 = ld16(base0 + 16 * 1152 + co);
        sc[0] = __builtin_amdgcn_mfma_f32_16x16x32_bf16(qf[f], k0, sc[0], 0, 0, 0);
        sc[1] = __builtin_amdgcn_mfma_f32_16x16x32_bf16(qf[f], k1, sc[1], 0, 0, 0);
      }
    }
    // mask + scale + online softmax
    float s0[4], s1[4], mt[4];
#pragma unroll
    for (int j = 0; j < 4; j++) {
      int qr_ = qrowD + j;
      s0[j] = (tb + lr <= qr_) ? sc[0][j] * scale : -INFINITY;
      s1[j] = (tb + 16 + lr <= qr_) ? sc[1][j] * scale : -INFINITY;
      mt[j] = fmaxf(s0[j], s1[j]);
    }
#pragma unroll
    for (int d = 1; d < 16; d <<= 1)
#pragma unroll
      for (int j = 0; j < 4; j++) mt[j] = fmaxf(mt[j], __shfl_xor(mt[j], d));
    float p0[4], p1[4], rs[4];
#pragma unroll
    for (int j = 0; j < 4; j++) {
      float mn = fmaxf(mrow[j], mt[j]);
      float fac = __expf(mrow[j] - mn);
      mrow[j] = mn;
      p0[j] = __expf(s0[j] - mn);
      p1[j] = __expf(s1[j] - mn);
      rs[j] = p0[j] + p1[j];
      lrow[j] *= fac;
#pragma unroll
      for (int ni = 0; ni < 8; ni++) O[ni][j] *= fac;
    }
#pragma unroll
    for (int d = 1; d < 16; d <<= 1)
#pragma unroll
      for (int j = 0; j < 4; j++) rs[j] += __shfl_xor(rs[j], d);
#pragma unroll
    for (int j = 0; j < 4; j++) lrow[j] += rs[j];
    // P -> LDS (per-wave region), re-read as A-fragment
    u16* pw = &Pl[wv][0][0];
#pragma unroll
    for (int j = 0; j < 4; j++) {
      pw[(lg * 4 + j) * 40 + lr] = f2bf(p0[j]);
      pw[(lg * 4 + j) * 40 + 16 + lr] = f2bf(p1[j]);
    }
    asm volatile("" ::: "memory");
    bf16x8 pf = ld16(((char*)pw) + lr * 80 + lg * 16);
    // PV
    const char* vb = ((const char*)&Vts[0][0]) + (cg * 128 + lr) * 64 + lg * 16;
#pragma unroll
    for (int ni = 0; ni < 8; ni++) {
      bf16x8 vf = ld16(vb + ni * 1024);
      O[ni] = __builtin_amdgcn_mfma_f32_16x16x32_bf16(pf, vf, O[ni], 0, 0, 0);
    }
  }

  // ---- P4: normalize O -> LDS, then ov = O @ wbV[h]^T ----
  __syncthreads();  // all waves done reading Ks/Vts
  float inv4[4];
#pragma unroll
  for (int j = 0; j < 4; j++) inv4[j] = 1.0f / lrow[j];
#pragma unroll
  for (int ni = 0; ni < 8; ni++)
#pragma unroll
    for (int j = 0; j < 4; j++)
      KQ[swz(qg * 16 + lg * 4 + j, cg * 128 + ni * 16 + lr)] =
          f2bf(O[ni][j] * inv4[j]);
  __syncthreads();
  f32x4 vacc[2];
  vacc[0] = f32x4{0.f, 0.f, 0.f, 0.f};
  vacc[1] = f32x4{0.f, 0.f, 0.f, 0.f};
#pragma unroll
  for (int ks = 0; ks < 16; ks++) {
    bf16x8 ao = ld16(&KQ[swz(qg * 16 + lr, ks * 32 + lg * 8)]);
#pragma unroll
    for (int ni = 0; ni < 2; ni++) {
      bf16x8 bw = ld16(wbV + ((long)h * 128 + cg * 32 + ni * 16 + lr) * 512 +
                       ks * 32 + lg * 8);
      vacc[ni] = __builtin_amdgcn_mfma_f32_16x16x32_bf16(ao, bw, vacc[ni], 0, 0, 0);
    }
  }
#pragma unroll
  for (int ni = 0; ni < 2; ni++)
#pragma unroll
    for (int j = 0; j < 4; j++)
      ov[((long)b * 2048 + qrowD + j) * 2048 + h * 128 + cg * 32 + ni * 16 + lr] =
          f2bf(vacc[ni][j]);
}

// =============================================================================
extern "C" void kernel_launch(void* const* d_in, const int* in_sizes, int n_in,
                              void* d_out, int out_size, void* d_ws, size_t ws_size,
                              hipStream_t stream) {
  const float* x     = (const float*)d_in[0];
  const float* wq    = (const float*)d_in[1];
  const float* wkva  = (const float*)d_in[2];
  const float* knw   = (const float*)d_in[3];
  const float* wkvb  = (const float*)d_in[4];
  const float* wo    = (const float*)d_in[5];
  const float* freqs = (const float*)d_in[6];
  float* out = (float*)d_out;

  char* ws = (char*)d_ws;
  size_t off = 0;
  auto alloc = [&](size_t bytes) {
    char* p = ws + off;
    off += (bytes + 255) & ~(size_t)255;
    return p;
  };
  // total ~101 MB, no aliasing
  u16* qn    = (u16*)alloc(8388608ull * 2);   // [4096][16][128]
  u16* xb    = (u16*)alloc(8388608ull * 2);   // [4096][2048]
  u16* wqb   = (u16*)alloc(6291456ull * 2);   // [3072][2048]
  u16* wkvab = (u16*)alloc(1310720ull * 2);   // [640][2048] (rows >=576 zero)
  float* kvf = (float*)alloc(2621440ull * 4); // [4096][640]
  u16* wbT   = (u16*)alloc(1048576ull * 2);   // [16][512][128]
  u16* wbV   = (u16*)alloc(1048576ull * 2);   // [16][128][512]
  u16* wob   = (u16*)alloc(4194304ull * 2);   // [2048][2048]
  u16* qpe_  = (u16*)alloc(4194304ull * 2);   // [4096][16][64]
  u16* kvn   = (u16*)alloc(2097152ull * 2);   // [4096][512]
  u16* kpe   = (u16*)alloc(262144ull * 2);    // [4096][64]
  u16* kvt   = (u16*)alloc(2097152ull * 2);   // [2][512][2048]
  u16* ovb   = (u16*)alloc(8388608ull * 2);   // [4096][2048]
  // qbig bf16 [4096][3072] lives in d_out (24 MB < 32 MB), dead before final GEMM
  u16* qbig = (u16*)d_out;

  if (off > ws_size) {  // debug channel: absmax ~= ws_size in MB
    fill_dbg<<<2048, 256, 0, stream>>>(out, 8388608L, (float)(ws_size >> 20));
    return;
  }

  double msc = 0.1 * log(40.0) + 1.0;
  float scale = (float)(pow(192.0, -0.5) * msc * msc);

  cast4<<<1024, 256, 0, stream>>>(x, xb, 8388608L, 8388608L);
  cast4<<<1024, 256, 0, stream>>>(wq, wqb, 6291456L, 6291456L);
  cast4<<<1024, 256, 0, stream>>>(wkva, wkvab, 1310720L, 1179648L);
  cast4<<<1024, 256, 0, stream>>>(wo, wob, 4194304L, 4194304L);
  prep_wkvb<<<2048, 256, 0, stream>>>(wkvb, wbT, wbV);

  // q = x @ wq^T (4096x3072, K=2048) -> bf16 in d_out
  gemm_bt<true><<<dim3(24, 32, 1), 256, 0, stream>>>(
      xb, 2048, wqb, 2048, qbig, 3072, 2048);
  // kv_full = x @ wkv_a^T (4096x640, K=2048) -> f32
  gemm_bt<false><<<dim3(5, 32, 1), 256, 0, stream>>>(
      xb, 2048, wkvab, 2048, kvf, 640, 2048);

  fixup_q<<<4096, 256, 0, stream>>>(qbig, freqs, qn, qpe_);
  fixup_kv<<<4096, 256, 0, stream>>>(kvf, knw, freqs, kvn, kpe);
  transpose_kv<<<dim3(64, 16, 2), 256, 0, stream>>>(kvn, kvt);

  // fused: q_absorb + flash attention + v-projection -> ov
  mla_flash<<<dim3(64, 16, 2), 512, 0, stream>>>(qn, qpe_, wbT, wbV, kvn, kpe,
                                                 kvt, ovb, scale);

  // out = ov @ wo^T (4096x2048, K=2048) -> f32 (overwrites qbig in d_out)
  gemm_bt<false><<<dim3(16, 32, 1), 256, 0, stream>>>(
      ovb, 2048, wob, 2048, out, 2048, 2048);
}

// Round 3
// 1166.027 us; speedup vs baseline: 1.2824x; 1.2824x over previous
//
#include <hip/hip_runtime.h>
#include <hip/hip_bf16.h>
#include <cmath>

typedef __bf16 bf16x8 __attribute__((ext_vector_type(8)));
typedef unsigned short u16x8_t __attribute__((ext_vector_type(8)));
typedef float f32x4 __attribute__((ext_vector_type(4)));
typedef unsigned short u16;

__device__ inline bf16x8 ld16(const void* p) {
  return __builtin_bit_cast(bf16x8, *reinterpret_cast<const u16x8_t*>(p));
}
__device__ inline void async16(const void* g, void* l) {
  __builtin_amdgcn_global_load_lds(
      (const __attribute__((address_space(1))) unsigned int*)g,
      (__attribute__((address_space(3))) unsigned int*)l, 16, 0, 0);
}
__device__ inline u16 f2bf(float v) {
  return __builtin_bit_cast(u16, __float2bfloat16(v));
}
__device__ inline float bf2f(u16 v) {
  unsigned int u = ((unsigned int)v) << 16;
  return __builtin_bit_cast(float, u);
}

// ---------------- cast f32 -> bf16 (vectorized, zero-pad past nsrc) ----------
__global__ void cast4(const float* __restrict__ src, u16* __restrict__ dst,
                      long n, long nsrc) {
  for (long i = (long)blockIdx.x * 256 + threadIdx.x; i * 4 < n;
       i += (long)gridDim.x * 256) {
    float4 v;
    if (i * 4 < nsrc) v = ((const float4*)src)[i];
    else { v.x = v.y = v.z = v.w = 0.f; }
    ushort4 o;
    o.x = f2bf(v.x); o.y = f2bf(v.y); o.z = f2bf(v.z); o.w = f2bf(v.w);
    ((ushort4*)dst)[i] = o;
  }
}

__global__ void fill_dbg(float* __restrict__ out, long n, float v) {
  for (long i = (long)blockIdx.x * 256 + threadIdx.x; i < n;
       i += (long)gridDim.x * 256) out[i] = v;
}

// ---------------- wkv_b -> per-head transposed nope part + v part ------------
__global__ void prep_wkvb(const float* __restrict__ in, u16* __restrict__ outT,
                          u16* __restrict__ outV) {
  int h = blockIdx.x >> 7, d = blockIdx.x & 127;
  const float* r0 = in + (long)(h * 256 + d) * 512;
  const float* r1 = in + (long)(h * 256 + 128 + d) * 512;
  for (int c = threadIdx.x; c < 512; c += 256) {
    outT[((long)h * 512 + c) * 128 + d] = f2bf(r0[c]);
    outV[((long)h * 128 + d) * 512 + c] = f2bf(r1[c]);
  }
}

// ---------------- generic C = A * B^T bf16 GEMM (m97 structure) --------------
template <bool OUT_BF16>
__global__ __launch_bounds__(256) void gemm_bt(
    const u16* __restrict__ A, long lda,
    const u16* __restrict__ B, long ldb,
    void* __restrict__ Cv, long ldc, int K) {
  const long m0 = (long)blockIdx.y * 128, n0 = (long)blockIdx.x * 128;
  __shared__ __align__(16) u16 As[128][32];
  __shared__ __align__(16) u16 Bs[128][32];
  const int tid = threadIdx.x, lane = tid & 63, wv = tid >> 6;
  const int wm = (wv >> 1) * 64, wn = (wv & 1) * 64;
  const int lr = lane & 15, lg = lane >> 4;
  f32x4 acc[4][4];
#pragma unroll
  for (int i = 0; i < 4; i++)
#pragma unroll
    for (int j = 0; j < 4; j++) acc[i][j] = f32x4{0.f, 0.f, 0.f, 0.f};
  const int rr = tid >> 2, ko = (tid & 3) * 8;
  for (int k0 = 0; k0 < K; k0 += 32) {
    __syncthreads();
    async16(A + (m0 + rr) * lda + k0 + ko, &As[rr][ko]);
    async16(A + (m0 + rr + 64) * lda + k0 + ko, &As[rr + 64][ko]);
    async16(B + (n0 + rr) * ldb + k0 + ko, &Bs[rr][ko]);
    async16(B + (n0 + rr + 64) * ldb + k0 + ko, &Bs[rr + 64][ko]);
    __syncthreads();
    bf16x8 af[4], bfr[4];
#pragma unroll
    for (int mi = 0; mi < 4; mi++) af[mi] = ld16(&As[wm + mi * 16 + lr][lg * 8]);
#pragma unroll
    for (int ni = 0; ni < 4; ni++) bfr[ni] = ld16(&Bs[wn + ni * 16 + lr][lg * 8]);
#pragma unroll
    for (int mi = 0; mi < 4; mi++)
#pragma unroll
      for (int ni = 0; ni < 4; ni++)
        acc[mi][ni] = __builtin_amdgcn_mfma_f32_16x16x32_bf16(
            af[mi], bfr[ni], acc[mi][ni], 0, 0, 0);
  }
#pragma unroll
  for (int mi = 0; mi < 4; mi++)
#pragma unroll
    for (int ni = 0; ni < 4; ni++)
#pragma unroll
      for (int j = 0; j < 4; j++) {
        long row = m0 + wm + mi * 16 + lg * 4 + j;
        long col = n0 + wn + ni * 16 + lr;
        long idx = row * ldc + col;
        if (OUT_BF16) ((u16*)Cv)[idx] = f2bf(acc[mi][ni][j]);
        else ((float*)Cv)[idx] = acc[mi][ni][j];
      }
}

// ---------------- q fixup: split nope/pe, RoPE pe (bf16 in) ------------------
__global__ void fixup_q(const u16* __restrict__ q, const float* __restrict__ freqs,
                        u16* __restrict__ qn, u16* __restrict__ qpe) {
  long row = blockIdx.x;
  int s = (int)(row & 2047);
  const u16* qr = q + row * 3072;
  for (int j = threadIdx.x; j < 2048; j += 256) {
    int h = j >> 7, d = j & 127;
    qn[row * 2048 + j] = qr[h * 192 + d];
  }
  for (int j = threadIdx.x; j < 1024; j += 256) {
    int h = j >> 6, t = j & 63, p = t >> 1;
    float ang = freqs[s * 32 + p];
    float co = cosf(ang), sn = sinf(ang);
    float x0 = bf2f(qr[h * 192 + 128 + 2 * p]);
    float x1 = bf2f(qr[h * 192 + 128 + 2 * p + 1]);
    float y = (t & 1) ? (x0 * sn + x1 * co) : (x0 * co - x1 * sn);
    qpe[row * 1024 + j] = f2bf(y);
  }
}

// ---------------- kv fixup: RMSNorm(kv)*w -> bf16, RoPE(k_pe) -> bf16 --------
__global__ void fixup_kv(const float* __restrict__ kvf, const float* __restrict__ w,
                         const float* __restrict__ freqs, u16* __restrict__ kvn,
                         u16* __restrict__ kpe) {
  long row = blockIdx.x;
  int s = (int)(row & 2047);
  const float* src = kvf + row * 640;
  int t = threadIdx.x;
  float x0 = src[t], x1 = src[t + 256];
  float ss = x0 * x0 + x1 * x1;
  for (int d = 1; d < 64; d <<= 1) ss += __shfl_xor(ss, d);
  __shared__ float wsum[4];
  if ((t & 63) == 0) wsum[t >> 6] = ss;
  __syncthreads();
  float tot = wsum[0] + wsum[1] + wsum[2] + wsum[3];
  float inv = rsqrtf(tot * (1.0f / 512.0f) + 1e-6f);
  kvn[row * 512 + t] = f2bf(x0 * inv * w[t]);
  kvn[row * 512 + t + 256] = f2bf(x1 * inv * w[t + 256]);
  if (t < 64) {
    int p = t >> 1;
    float ang = freqs[s * 32 + p];
    float co = cosf(ang), sn = sinf(ang);
    float a0 = src[512 + 2 * p], a1 = src[512 + 2 * p + 1];
    float y = (t & 1) ? (a0 * sn + a1 * co) : (a0 * co - a1 * sn);
    kpe[row * 64 + t] = f2bf(y);
  }
}

// ---------------- kvn [4096][512] -> kvt [2][512][2048] (per-batch T) --------
__global__ void transpose_kv(const u16* __restrict__ kvn, u16* __restrict__ kvt) {
  __shared__ u16 T[32][33];
  int b = blockIdx.z;
  int s0 = blockIdx.x * 32, c0 = blockIdx.y * 32;
  int r = threadIdx.x >> 5, c = threadIdx.x & 31;
  for (int rr = r; rr < 32; rr += 8)
    T[rr][c] = kvn[((long)b * 2048 + s0 + rr) * 512 + c0 + c];
  __syncthreads();
  for (int rr = r; rr < 32; rr += 8)
    kvt[((long)b * 512 + c0 + rr) * 2048 + s0 + c] = T[c][rr];
}

// ---------------- fused flash MLA attention (KVBLK=64, no redundant MFMA) ----
// Block: 32 q-rows x head h x batch b. 8 waves = (qg 0..1) x (cg 0..3).
// QK: wave (qg,cg) computes distinct 16x16 scores (rows qg*16, cols cg*16)
// over K=576 (18 MFMA). Cross-wave softmax via Msh/Lsh partials. P via
// swizzled Psh[32][64]. PV: wave handles vcols cg*128..+128 (16 MFMA).
__device__ inline int swz(int row, int col) {  // within [32][512] u16 tile
  return row * 512 + ((((col >> 3) ^ (row & 7)) << 3) | (col & 7));
}

__global__ __launch_bounds__(512, 2) void mla_flash(
    const u16* __restrict__ qn, const u16* __restrict__ qpe,
    const u16* __restrict__ wbT, const u16* __restrict__ wbV,
    const u16* __restrict__ kvn, const u16* __restrict__ kpe,
    const u16* __restrict__ kvt, u16* __restrict__ ov, float scale) {
  __shared__ __align__(16) u16 Ks[64][576];   // 73728 B, chunk-XOR swizzled
  __shared__ __align__(16) u16 Vts[512][64];  // 65536 B, chunk-XOR swizzled
  __shared__ __align__(16) u16 Psh[32][64];   // 4096 B, chunk-XOR swizzled
  __shared__ float Msh[32][4];
  __shared__ float Lsh[32][4];
  u16* KQ = &Ks[0][0];  // overlay: Qa / Ot [32][512] swizzled (32768 B)
  u16* Pp = &Psh[0][0];

  const int qb = (63 - blockIdx.x) * 32;  // longest blocks first
  const int h = blockIdx.y, b = blockIdx.z;
  const int tid = threadIdx.x, lane = tid & 63, wv = tid >> 6;
  const int qg = wv >> 2, cg = wv & 3;
  const int lr = lane & 15, lg = lane >> 4;
  const long rowA = (long)b * 2048 + qb + qg * 16 + lr;  // A-frag q row
  const int rloc = qg * 16 + lg * 4;                     // in-tile D-frag row
  const int qrowD = qb + rloc;                           // global D-frag row

  // ---- P1: q_abs tile -> KQ (swizzled) ----
  {
    f32x4 qacc[8];
#pragma unroll
    for (int i = 0; i < 8; i++) qacc[i] = f32x4{0.f, 0.f, 0.f, 0.f};
#pragma unroll
    for (int ks = 0; ks < 4; ks++) {
      bf16x8 aq = ld16(qn + rowA * 2048 + h * 128 + ks * 32 + lg * 8);
#pragma unroll
      for (int ni = 0; ni < 8; ni++) {
        bf16x8 bw = ld16(wbT + ((long)h * 512 + cg * 128 + ni * 16 + lr) * 128 +
                         ks * 32 + lg * 8);
        qacc[ni] = __builtin_amdgcn_mfma_f32_16x16x32_bf16(aq, bw, qacc[ni], 0, 0, 0);
      }
    }
#pragma unroll
    for (int ni = 0; ni < 8; ni++)
#pragma unroll
      for (int j = 0; j < 4; j++)
        KQ[swz(rloc + j, cg * 128 + ni * 16 + lr)] = f2bf(qacc[ni][j]);
  }
  __syncthreads();

  // ---- P2: Q fragments (A-operand) ----
  bf16x8 qf[18];
#pragma unroll
  for (int f = 0; f < 16; f++)
    qf[f] = ld16(&KQ[swz(qg * 16 + lr, f * 32 + lg * 8)]);
  {
    const u16* qp = qpe + rowA * 1024 + h * 64 + lg * 8;
    qf[16] = ld16(qp);
    qf[17] = ld16(qp + 32);
  }

  f32x4 O[8];
#pragma unroll
  for (int i = 0; i < 8; i++) O[i] = f32x4{0.f, 0.f, 0.f, 0.f};
  float mrow[4], lrow[4];
#pragma unroll
  for (int j = 0; j < 4; j++) { mrow[j] = -INFINITY; lrow[j] = 0.f; }

  const int nt = qb / 64 + 1;
  for (int t = 0; t < nt; t++) {
    const int tb = t * 64;
    __syncthreads();  // B1: prev tile fully consumed
    // stage K-tile [64][576], 16B-chunk swizzle o ^= (r&7)
    for (int c = tid; c < 4608; c += 512) {
      int r = c / 72, o = c - r * 72;
      int og = o ^ (r & 7);
      long grow = (long)b * 2048 + tb + r;
      const u16* src = (og < 64) ? (kvn + grow * 512 + og * 8)
                                 : (kpe + grow * 64 + (og - 64) * 8);
      async16(src, ((char*)Ks) + (long)c * 16);
    }
    // stage V^T tile [512][64], chunk swizzle
    for (int c = tid; c < 4096; c += 512) {
      int r = c >> 3, o = c & 7;
      int og = o ^ (r & 7);
      const u16* src = kvt + ((long)b * 512 + r) * 2048 + tb + og * 8;
      async16(src, ((char*)Vts) + (long)c * 16);
    }
    __syncthreads();  // B2: staging done

    // QK: distinct 16x16 per wave (cols cg*16+lr)
    f32x4 sc = f32x4{0.f, 0.f, 0.f, 0.f};
    {
      const char* kbase = ((const char*)Ks) + (cg * 16 + lr) * 1152;
      const int sx = lr & 7;
#pragma unroll
      for (int f = 0; f < 18; f++) {
        bf16x8 kf = ld16(kbase + (((f * 4 + lg) ^ sx) * 16));
        sc = __builtin_amdgcn_mfma_f32_16x16x32_bf16(qf[f], kf, sc, 0, 0, 0);
      }
    }
    // mask + scale + local (16-col) max
    float s4[4], mt[4];
    const int colg = tb + cg * 16 + lr;
#pragma unroll
    for (int j = 0; j < 4; j++) {
      s4[j] = (colg <= qrowD + j) ? sc[j] * scale : -INFINITY;
      mt[j] = s4[j];
    }
#pragma unroll
    for (int d = 1; d < 16; d <<= 1)
#pragma unroll
      for (int j = 0; j < 4; j++) mt[j] = fmaxf(mt[j], __shfl_xor(mt[j], d));
    if (lr == 0)
#pragma unroll
      for (int j = 0; j < 4; j++) Msh[rloc + j][cg] = mt[j];
    __syncthreads();  // B3: all max partials visible

    float fac[4], p4[4], ls[4];
#pragma unroll
    for (int j = 0; j < 4; j++) {
      float4 m4 = *(const float4*)Msh[rloc + j];
      float mn = fmaxf(fmaxf(fmaxf(m4.x, m4.y), fmaxf(m4.z, m4.w)), mrow[j]);
      fac[j] = __expf(mrow[j] - mn);
      mrow[j] = mn;
      p4[j] = __expf(s4[j] - mn);
      ls[j] = p4[j];
    }
#pragma unroll
    for (int d = 1; d < 16; d <<= 1)
#pragma unroll
      for (int j = 0; j < 4; j++) ls[j] += __shfl_xor(ls[j], d);
    if (lr == 0)
#pragma unroll
      for (int j = 0; j < 4; j++) Lsh[rloc + j][cg] = ls[j];
    // write P tile (swizzled chunks) + rescale O
#pragma unroll
    for (int j = 0; j < 4; j++) {
      int row = rloc + j;
      int chunk = (cg * 2 + (lr >> 3)) ^ (row & 7);
      Pp[row * 64 + chunk * 8 + (lr & 7)] = f2bf(p4[j]);
#pragma unroll
      for (int ni = 0; ni < 8; ni++) O[ni][j] *= fac[j];
    }
    __syncthreads();  // B4: P + l partials visible

#pragma unroll
    for (int j = 0; j < 4; j++) {
      float4 l4 = *(const float4*)Lsh[rloc + j];
      lrow[j] = lrow[j] * fac[j] + (l4.x + l4.y + l4.z + l4.w);
    }
    // P A-frags: row = qg*16+lr, kcols ks*32+lg*8
    bf16x8 pf[2];
#pragma unroll
    for (int ks = 0; ks < 2; ks++)
      pf[ks] = ld16(&Pp[(qg * 16 + lr) * 64 + (((ks * 4 + lg) ^ (lr & 7)) * 8)]);
    // PV: vcols cg*128..+128
    const char* vbase = (const char*)Vts;
#pragma unroll
    for (int ks = 0; ks < 2; ks++)
#pragma unroll
      for (int ni = 0; ni < 8; ni++) {
        int row = cg * 128 + ni * 16 + lr;
        bf16x8 vf = ld16(vbase + row * 128 + (((ks * 4 + lg) ^ (lr & 7)) * 16));
        O[ni] = __builtin_amdgcn_mfma_f32_16x16x32_bf16(pf[ks], vf, O[ni], 0, 0, 0);
      }
  }

  // ---- P4: normalize O -> KQ, then ov = O @ wbV[h]^T ----
  __syncthreads();
  float inv4[4];
#pragma unroll
  for (int j = 0; j < 4; j++) inv4[j] = 1.0f / lrow[j];
#pragma unroll
  for (int ni = 0; ni < 8; ni++)
#pragma unroll
    for (int j = 0; j < 4; j++)
      KQ[swz(rloc + j, cg * 128 + ni * 16 + lr)] = f2bf(O[ni][j] * inv4[j]);
  __syncthreads();
  f32x4 vacc[2];
  vacc[0] = f32x4{0.f, 0.f, 0.f, 0.f};
  vacc[1] = f32x4{0.f, 0.f, 0.f, 0.f};
#pragma unroll
  for (int ks = 0; ks < 16; ks++) {
    bf16x8 ao = ld16(&KQ[swz(qg * 16 + lr, ks * 32 + lg * 8)]);
#pragma unroll
    for (int ni = 0; ni < 2; ni++) {
      bf16x8 bw = ld16(wbV + ((long)h * 128 + cg * 32 + ni * 16 + lr) * 512 +
                       ks * 32 + lg * 8);
      vacc[ni] = __builtin_amdgcn_mfma_f32_16x16x32_bf16(ao, bw, vacc[ni], 0, 0, 0);
    }
  }
#pragma unroll
  for (int ni = 0; ni < 2; ni++)
#pragma unroll
    for (int j = 0; j < 4; j++)
      ov[((long)b * 2048 + qrowD + j) * 2048 + h * 128 + cg * 32 + ni * 16 + lr] =
          f2bf(vacc[ni][j]);
}

// =============================================================================
extern "C" void kernel_launch(void* const* d_in, const int* in_sizes, int n_in,
                              void* d_out, int out_size, void* d_ws, size_t ws_size,
                              hipStream_t stream) {
  const float* x     = (const float*)d_in[0];
  const float* wq    = (const float*)d_in[1];
  const float* wkva  = (const float*)d_in[2];
  const float* knw   = (const float*)d_in[3];
  const float* wkvb  = (const float*)d_in[4];
  const float* wo    = (const float*)d_in[5];
  const float* freqs = (const float*)d_in[6];
  float* out = (float*)d_out;

  char* ws = (char*)d_ws;
  size_t off = 0;
  auto alloc = [&](size_t bytes) {
    char* p = ws + off;
    off += (bytes + 255) & ~(size_t)255;
    return p;
  };
  u16* qn    = (u16*)alloc(8388608ull * 2);   // [4096][16][128]
  u16* xb    = (u16*)alloc(8388608ull * 2);   // [4096][2048]
  u16* wqb   = (u16*)alloc(6291456ull * 2);   // [3072][2048]
  u16* wkvab = (u16*)alloc(1310720ull * 2);   // [640][2048] (rows >=576 zero)
  float* kvf = (float*)alloc(2621440ull * 4); // [4096][640]
  u16* wbT   = (u16*)alloc(1048576ull * 2);   // [16][512][128]
  u16* wbV   = (u16*)alloc(1048576ull * 2);   // [16][128][512]
  u16* wob   = (u16*)alloc(4194304ull * 2);   // [2048][2048]
  u16* qpe_  = (u16*)alloc(4194304ull * 2);   // [4096][16][64]
  u16* kvn   = (u16*)alloc(2097152ull * 2);   // [4096][512]
  u16* kpe   = (u16*)alloc(262144ull * 2);    // [4096][64]
  u16* kvt   = (u16*)alloc(2097152ull * 2);   // [2][512][2048]
  u16* ovb   = (u16*)alloc(8388608ull * 2);   // [4096][2048]
  u16* qbig = (u16*)d_out;  // bf16 [4096][3072] in d_out, dead before final GEMM

  if (off > ws_size) {
    fill_dbg<<<2048, 256, 0, stream>>>(out, 8388608L, (float)(ws_size >> 20));
    return;
  }

  double msc = 0.1 * log(40.0) + 1.0;
  float scale = (float)(pow(192.0, -0.5) * msc * msc);

  cast4<<<1024, 256, 0, stream>>>(x, xb, 8388608L, 8388608L);
  cast4<<<1024, 256, 0, stream>>>(wq, wqb, 6291456L, 6291456L);
  cast4<<<1024, 256, 0, stream>>>(wkva, wkvab, 1310720L, 1179648L);
  cast4<<<1024, 256, 0, stream>>>(wo, wob, 4194304L, 4194304L);
  prep_wkvb<<<2048, 256, 0, stream>>>(wkvb, wbT, wbV);

  gemm_bt<true><<<dim3(24, 32, 1), 256, 0, stream>>>(
      xb, 2048, wqb, 2048, qbig, 3072, 2048);
  gemm_bt<false><<<dim3(5, 32, 1), 256, 0, stream>>>(
      xb, 2048, wkvab, 2048, kvf, 640, 2048);

  fixup_q<<<4096, 256, 0, stream>>>(qbig, freqs, qn, qpe_);
  fixup_kv<<<4096, 256, 0, stream>>>(kvf, knw, freqs, kvn, kpe);
  transpose_kv<<<dim3(64, 16, 2), 256, 0, stream>>>(kvn, kvt);

  mla_flash<<<dim3(64, 16, 2), 512, 0, stream>>>(qn, qpe_, wbT, wbV, kvn, kpe,
                                                 kvt, ovb, scale);

  gemm_bt<false><<<dim3(16, 32, 1), 256, 0, stream>>>(
      ovb, 2048, wob, 2048, out, 2048, 2048);
}